// Round 10
// baseline (470.129 us; speedup 1.0000x reference)
//
#include <hip/hip_runtime.h>
#include <cstdint>
#include <cstddef>

typedef __attribute__((ext_vector_type(4)))  int   i32x4;
typedef __attribute__((ext_vector_type(16))) int   i32x16;
typedef __attribute__((ext_vector_type(4)))  float f32x4;

// Problem dims (fixed by setup_inputs: B=8, S=2048, K=4096, O=4096)
#define M_DIM 16384
#define N_DIM 4096
#define K_DIM 4096
#define NT    (K_DIM / 128)   // 32 K-tiles of 128 int8 (= 4 MFMA K=32 slices)

// Compiler-fenced barrier (full compiler memory fence at each rendezvous).
#define BARRIER() asm volatile("s_barrier" ::: "memory")

// ---------------------------------------------------------------------------
// quantize x (per-tensor): xq = clip(rint(x/s)+zp, -128,127) - zp
// ---------------------------------------------------------------------------
__global__ __launch_bounds__(256) void quant_x_kernel(
    const float* __restrict__ x,
    const float* __restrict__ act_scale,
    const int*   __restrict__ act_zp,
    signed char* __restrict__ xq)
{
    int idx = blockIdx.x * 256 + threadIdx.x;      // one thread per 16 elems
    float s   = act_scale[0];
    float zpf = (float)act_zp[0];
    const f32x4* xp = (const f32x4*)(x + (size_t)idx * 16);
    union { signed char c[16]; i32x4 v; } u;
#pragma unroll
    for (int j = 0; j < 4; ++j) {
        f32x4 v = xp[j];
#pragma unroll
        for (int e = 0; e < 4; ++e) {
            float q = rintf(v[e] / s) + zpf;          // round-half-even like np.round
            q = fminf(fmaxf(q, -128.f), 127.f);
            u.c[j * 4 + e] = (signed char)(int)(q - zpf);
        }
    }
    *(i32x4*)(xq + (size_t)idx * 16) = u.v;
}

// ---------------------------------------------------------------------------
// quantize weight (per-output-row scale/zp). K_DIM=4096 -> 256 threads/row.
// ---------------------------------------------------------------------------
__global__ __launch_bounds__(256) void quant_w_kernel(
    const float* __restrict__ w,
    const float* __restrict__ wscale,
    const int*   __restrict__ wzp,
    signed char* __restrict__ wq)
{
    int idx = blockIdx.x * 256 + threadIdx.x;
    int row = idx >> 8;                             // 4096/16 = 256 chunks per row
    float s   = wscale[row];
    float zpf = (float)wzp[row];
    const f32x4* wp = (const f32x4*)(w + (size_t)idx * 16);
    union { signed char c[16]; i32x4 v; } u;
#pragma unroll
    for (int j = 0; j < 4; ++j) {
        f32x4 v = wp[j];
#pragma unroll
        for (int e = 0; e < 4; ++e) {
            float q = rintf(v[e] / s) + zpf;
            q = fminf(fmaxf(q, -128.f), 127.f);
            u.c[j * 4 + e] = (signed char)(int)(q - zpf);
        }
    }
    *(i32x4*)(wq + (size_t)idx * 16) = u.v;
}

// ---------------------------------------------------------------------------
// int8 GEMM 256x256, mfma_i32_32x32x32_i8, DOUBLE-BUFFERED LDS, ONE barrier
// per K-tile.
//
// Round-9 lessons: (a) LDS traffic (192KB read + 64KB write per block-tile
// ~= 2000-2760cy) is on par with the MFMA floor (2340cy) -> they MUST
// overlap; per-phase barriers serialize them. (b) the 32B-row swizzle had a
// residual 4cy/read conflict (quad partners l/l+16 shared slot).
//
// Structure: stages always target the OTHER buffer -> zero intra-tile
// cross-wave hazards -> no intra-tile barriers. Within a tile, 24 ds_reads
// and 32 MFMAs flow with compiler-counted lgkmcnt (reads of slice s+1 drain
// under MFMA of slice s; ping-pong frag sets; sched_barrier(0) seals slice
// regions to cap live regs ~206 < 256). Tile end: lgkmcnt(0) [all reads of
// cur buf retired -> WAR for stage t+2 next tile], vmcnt(0) [stages of t+1,
// issued a full tile (~2800cy) earlier, retired -> RAW; wait ~= 0], barrier.
//
// LDS layout (conflict-free, matches round-3's measured-zero properties):
// unit = 32 rows x 32B K-slice = 1024B = 8 lines of 128B.
//   byte(row, g) = line*128 + slot*16, line = row&7,
//   slot = line ^ (g<<2) ^ ((row>>3)&3)     (g = 16B half, bijective/line)
// Read (lane: row=lane&31, g=lane>>5): 8-lane runs -> slots {0..7}^c = all
// 32 banks; stride-8/16/32 lane partners -> distinct slots (fixes round 9).
// Write: global_load_lds lane-linear (lane l -> unit byte l*16); inverse map
// folded into per-lane GLOBAL source: srow = ((l^(l>>3))&3)*8 + ((l>>3)&7),
// sg = ((l>>2)^(l>>5))&1.
// A tile = 32 units (rb 0..7 x ks 0..3) at (rb*4+ks)*1024; B same +32768.
// Wave w stages A units (w, ks 0..3) + B units (w, ks 0..3) = 8 loads/tile.
//
// mfma_i32_32x32x32_i8 (HW-verified rounds 8/9): per wave 4 mf x 2 nf,
// output 128x64, acc 128 AGPR. launch_bounds (512,2): 256 regs/wave
// (round-8 lesson: (512,4) halves the budget -> acc spills catastrophically).
// ---------------------------------------------------------------------------
__global__ __launch_bounds__(512, 2) void gemm_i8_256(
    const signed char* __restrict__ Aq,
    const signed char* __restrict__ Bq,
    const float* __restrict__ bias,
    const float* __restrict__ act_scale,
    const float* __restrict__ wscale,
    float* __restrict__ out)
{
    __shared__ signed char lds[131072];   // 2 x (A 32KB + B 32KB)

    const int nbn = N_DIM / 256;                 // 16
    const int nwg = (M_DIM / 256) * nbn;         // 1024, %8==0
    int bid = blockIdx.x;
    int wg  = (bid & 7) * (nwg >> 3) + (bid >> 3);   // T1 XCD swizzle, bijective
    int bm  = wg / nbn;
    int bn  = wg % nbn;

    int tid  = threadIdx.x;
    int wave = tid >> 6;
    int lane = tid & 63;
    int wm_i = wave >> 2;      // 0..1  (128-row half)
    int wn_i = wave & 3;       // 0..3  (64-col quarter)

    const signed char* Ag = Aq + (size_t)bm * 256 * K_DIM;
    const signed char* Bg = Bq + (size_t)bn * 256 * K_DIM;

    // ---- staging source (per-lane inverse of the LDS layout) --------------
    int srow = ((lane ^ (lane >> 3)) & 3) * 8 + ((lane >> 3) & 7);
    int sg   = ((lane >> 2) ^ (lane >> 5)) & 1;
    size_t rowK = (size_t)srow * K_DIM + sg * 16;
    const signed char* Asrc = Ag + (size_t)(wave * 32) * K_DIM + rowK;
    const signed char* Bsrc = Bg + (size_t)(wave * 32) * K_DIM + rowK;

    // ---- reader per-lane offset within a unit ------------------------------
    int laneoff = (lane & 7) * 128
                + (((lane & 7) ^ ((lane >> 5) << 2) ^ ((lane >> 3) & 3)) * 16);
    int abase = wm_i * 16384;            // + mf*4096 + ks*1024 + laneoff
    int bbase = 32768 + wn_i * 8192;     // + nf*4096 + ks*1024 + laneoff

    // stage all 8 units of K-tile `tile` into buffer at dbase
#define STAGE_TILE(tile, dbase) do {                                                 \
    _Pragma("unroll")                                                                \
    for (int ks = 0; ks < 4; ++ks) {                                                 \
        __builtin_amdgcn_global_load_lds(                                            \
            (const __attribute__((address_space(1))) void*)                          \
                (Asrc + (size_t)(tile) * 128 + ks * 32),                             \
            (__attribute__((address_space(3))) void*)                                \
                (lds + (dbase) + (wave * 4 + ks) * 1024), 16, 0, 0);                 \
        __builtin_amdgcn_global_load_lds(                                            \
            (const __attribute__((address_space(1))) void*)                          \
                (Bsrc + (size_t)(tile) * 128 + ks * 32),                             \
            (__attribute__((address_space(3))) void*)                                \
                (lds + (dbase) + 32768 + (wave * 4 + ks) * 1024), 16, 0, 0);         \
    }                                                                                \
} while (0)

#define READ_SET(AF, BF, cbase, ks) do {                                             \
    _Pragma("unroll")                                                                \
    for (int mf = 0; mf < 4; ++mf)                                                   \
        AF[mf] = *(const i32x4*)(lds + (cbase) + abase + mf * 4096                   \
                                 + (ks) * 1024 + laneoff);                           \
    _Pragma("unroll")                                                                \
    for (int nf = 0; nf < 2; ++nf)                                                   \
        BF[nf] = *(const i32x4*)(lds + (cbase) + bbase + nf * 4096                   \
                                 + (ks) * 1024 + laneoff);                           \
} while (0)

#define MFMA_SET(AF, BF) do {                                                        \
    _Pragma("unroll")                                                                \
    for (int mf = 0; mf < 4; ++mf)                                                   \
        _Pragma("unroll")                                                            \
        for (int nf = 0; nf < 2; ++nf)                                               \
            acc[mf][nf] = __builtin_amdgcn_mfma_i32_32x32x32_i8(                     \
                AF[mf], BF[nf], acc[mf][nf], 0, 0, 0);                               \
} while (0)

    i32x16 acc[4][2] = {};
    i32x4 aE[4], bE[2], aO[4], bO[2];   // ping-pong frag sets

    // ---- prologue: stage tile 0 into buffer 0 ------------------------------
    STAGE_TILE(0, 0);
    asm volatile("s_waitcnt vmcnt(0)" ::: "memory");
    BARRIER();

    for (int t = 0; t < NT; ++t) {
        const int cb = (t & 1) * 65536;      // compute buffer
        const int nb = cb ^ 65536;           // stage target

        if (t + 1 < NT) STAGE_TILE(t + 1, nb);

        READ_SET(aE, bE, cb, 0);
        READ_SET(aO, bO, cb, 1);
        __builtin_amdgcn_s_setprio(1); MFMA_SET(aE, bE);   // ks 0
        __builtin_amdgcn_s_setprio(0);
        __builtin_amdgcn_sched_barrier(0);

        READ_SET(aE, bE, cb, 2);
        __builtin_amdgcn_s_setprio(1); MFMA_SET(aO, bO);   // ks 1
        __builtin_amdgcn_s_setprio(0);
        __builtin_amdgcn_sched_barrier(0);

        READ_SET(aO, bO, cb, 3);
        __builtin_amdgcn_s_setprio(1); MFMA_SET(aE, bE);   // ks 2
        __builtin_amdgcn_s_setprio(0);
        __builtin_amdgcn_sched_barrier(0);

        __builtin_amdgcn_s_setprio(1); MFMA_SET(aO, bO);   // ks 3
        __builtin_amdgcn_s_setprio(0);

        if (t + 1 < NT) {
            // all my ds_reads of cb retired (WAR for stage t+2 into cb) +
            // all waves' stages of t+1 retired (RAW for next tile's reads).
            asm volatile("s_waitcnt lgkmcnt(0) vmcnt(0)" ::: "memory");
            BARRIER();
        }
    }
#undef MFMA_SET
#undef READ_SET
#undef STAGE_TILE

    // ---- epilogue: out = acc * (sa * sw[o]) + bias[o] ----------------------
    float sa = act_scale[0];
#pragma unroll
    for (int nf = 0; nf < 2; ++nf) {
        int o = bn * 256 + wn_i * 64 + nf * 32 + (lane & 31);
        float sw = sa * wscale[o];
        float bv = bias[o];
#pragma unroll
        for (int mf = 0; mf < 4; ++mf) {
            int rowb = bm * 256 + wm_i * 128 + mf * 32 + 4 * (lane >> 5);
#pragma unroll
            for (int r = 0; r < 16; ++r) {
                int grow = rowb + (r & 3) + 8 * (r >> 2);
                out[(size_t)grow * N_DIM + o] = (float)acc[mf][nf][r] * sw + bv;
            }
        }
    }
}

// ---------------------------------------------------------------------------
// insurance fallback if ws_size < 80MB (should never trigger)
// ---------------------------------------------------------------------------
__global__ void fallback_kernel(
    const float* __restrict__ x, const float* __restrict__ w,
    const float* __restrict__ bias,
    const float* __restrict__ act_scale, const float* __restrict__ wscale,
    const int* __restrict__ act_zp, const int* __restrict__ wzp,
    float* __restrict__ out)
{
    size_t idx = (size_t)blockIdx.x * blockDim.x + threadIdx.x;
    if (idx >= (size_t)M_DIM * N_DIM) return;
    int m = (int)(idx >> 12);
    int o = (int)(idx & 4095);
    float sx = act_scale[0], zx = (float)act_zp[0];
    float sw = wscale[o],    zw = (float)wzp[o];
    float acc = 0.f;
    for (int k = 0; k < K_DIM; ++k) {
        float qx = fminf(fmaxf(rintf(x[(size_t)m * K_DIM + k] / sx) + zx, -128.f), 127.f) - zx;
        float qw = fminf(fmaxf(rintf(w[(size_t)o * K_DIM + k] / sw) + zw, -128.f), 127.f) - zw;
        acc += (qx * sx) * (qw * sw);
    }
    out[idx] = acc + bias[o];
}

// ---------------------------------------------------------------------------
extern "C" void kernel_launch(void* const* d_in, const int* in_sizes, int n_in,
                              void* d_out, int out_size, void* d_ws, size_t ws_size,
                              hipStream_t stream)
{
    const float* x    = (const float*)d_in[0];
    const float* w    = (const float*)d_in[1];
    const float* bias = (const float*)d_in[2];
    const float* asc  = (const float*)d_in[3];
    const float* wsc  = (const float*)d_in[4];
    const int*   azp  = (const int*)d_in[5];
    const int*   wzp  = (const int*)d_in[6];
    float* out = (float*)d_out;

    size_t xq_bytes = (size_t)M_DIM * K_DIM;   // 64 MiB
    size_t wq_bytes = (size_t)N_DIM * K_DIM;   // 16 MiB

    if (ws_size < xq_bytes + wq_bytes) {
        int total = M_DIM * N_DIM;
        fallback_kernel<<<(total + 255) / 256, 256, 0, stream>>>(
            x, w, bias, asc, wsc, azp, wzp, out);
        return;
    }

    signed char* xq = (signed char*)d_ws;
    signed char* wq = (signed char*)d_ws + xq_bytes;

    quant_x_kernel<<<(M_DIM * (K_DIM / 16)) / 256, 256, 0, stream>>>(x, asc, azp, xq);
    quant_w_kernel<<<(N_DIM * (K_DIM / 16)) / 256, 256, 0, stream>>>(w, wsc, wzp, wq);
    gemm_i8_256<<<(M_DIM / 256) * (N_DIM / 256), 512, 0, stream>>>(
        xq, wq, bias, asc, wsc, out);
}

// Round 11
// 454.732 us; speedup vs baseline: 1.0339x; 1.0339x over previous
//
#include <hip/hip_runtime.h>
#include <cstdint>
#include <cstddef>

typedef __attribute__((ext_vector_type(4)))  int   i32x4;
typedef __attribute__((ext_vector_type(16))) int   i32x16;
typedef __attribute__((ext_vector_type(4)))  float f32x4;

// Problem dims (fixed by setup_inputs: B=8, S=2048, K=4096, O=4096)
#define M_DIM 16384
#define N_DIM 4096
#define K_DIM 4096
#define NT2   (K_DIM / 64)    // 64 K-tiles of 64 int8 (= 2 MFMA K=32 slices)

// Compiler-fenced barrier (full compiler memory fence at each rendezvous).
#define BARRIER() asm volatile("s_barrier" ::: "memory")

// ---------------------------------------------------------------------------
// quantize x (per-tensor): xq = clip(rint(x/s)+zp, -128,127) - zp
// ---------------------------------------------------------------------------
__global__ __launch_bounds__(256) void quant_x_kernel(
    const float* __restrict__ x,
    const float* __restrict__ act_scale,
    const int*   __restrict__ act_zp,
    signed char* __restrict__ xq)
{
    int idx = blockIdx.x * 256 + threadIdx.x;      // one thread per 16 elems
    float s   = act_scale[0];
    float zpf = (float)act_zp[0];
    const f32x4* xp = (const f32x4*)(x + (size_t)idx * 16);
    union { signed char c[16]; i32x4 v; } u;
#pragma unroll
    for (int j = 0; j < 4; ++j) {
        f32x4 v = xp[j];
#pragma unroll
        for (int e = 0; e < 4; ++e) {
            float q = rintf(v[e] / s) + zpf;          // round-half-even like np.round
            q = fminf(fmaxf(q, -128.f), 127.f);
            u.c[j * 4 + e] = (signed char)(int)(q - zpf);
        }
    }
    *(i32x4*)(xq + (size_t)idx * 16) = u.v;
}

// ---------------------------------------------------------------------------
// quantize weight (per-output-row scale/zp). K_DIM=4096 -> 256 threads/row.
// ---------------------------------------------------------------------------
__global__ __launch_bounds__(256) void quant_w_kernel(
    const float* __restrict__ w,
    const float* __restrict__ wscale,
    const int*   __restrict__ wzp,
    signed char* __restrict__ wq)
{
    int idx = blockIdx.x * 256 + threadIdx.x;
    int row = idx >> 8;                             // 4096/16 = 256 chunks per row
    float s   = wscale[row];
    float zpf = (float)wzp[row];
    const f32x4* wp = (const f32x4*)(w + (size_t)idx * 16);
    union { signed char c[16]; i32x4 v; } u;
#pragma unroll
    for (int j = 0; j < 4; ++j) {
        f32x4 v = wp[j];
#pragma unroll
        for (int e = 0; e < 4; ++e) {
            float q = rintf(v[e] / s) + zpf;
            q = fminf(fmaxf(q, -128.f), 127.f);
            u.c[j * 4 + e] = (signed char)(int)(q - zpf);
        }
    }
    *(i32x4*)(wq + (size_t)idx * 16) = u.v;
}

// ---------------------------------------------------------------------------
// int8 GEMM 256x256, mfma_i32_32x32x32_i8, 4-BUFFER RING, 3-TILE STAGE LEAD,
// COUNTED vmcnt (never 0 until the tail).
//
// Round-10 lesson: with vmcnt(0) per tile and only a same-tile stage lead,
// each tile stalls ~5000cy on staging-load latency (HBM ~900cy + queueing;
// working set per XCD ~18MB >> 4MB L2) -- at 1 block/CU nothing hides it.
// R3/R7 (counted vmcnt, 1-2 tile lead) ran 5530cy/tile vs R10's 7875.
//
// Fix: BK=64 -> tile 32KB -> ring of 4 buffers (128KB). During tile t stage
// tile t+3 into buf (t+3)&3 (held t-1; its readers lgkm-drained before the
// barrier ending t-1 -> WAR safe for ALL waves). Tile end: lgkmcnt(0) [own
// reads done] + vmcnt(8) [retires S(t+1), issued 3 tile-bodies (~4800cy)
// earlier -> latency covered; leaves S(t+2),S(t+3) in flight] + barrier.
// Tail: vmcnt(4) @ t=NT2-3, vmcnt(0) @ t=NT2-2, none @ NT2-1.
// Per wave per tile: 4 stages, 12 ds_read_b128, 16 MFMA, 1 barrier.
//
// LDS unit layout: IDENTICAL to round 10 (measured SQ_LDS_BANK_CONFLICT=0,
// absmax 1.0). Unit = 32 rows x 32B = 1024B, 8 lines x 128B:
//   read laneoff = (lane&7)*128 + (((lane&7)^((lane>>5)<<2)^((lane>>3)&3))*16)
//   stage inverse: srow = ((l^(l>>3))&3)*8 + ((l>>3)&7), sg=((l>>2)^(l>>5))&1
// Buffer (32KB): A units (rb 0..7 x ks 0..1) at (rb*2+ks)*1024; B at +16384.
// Wave w stages A(rb=w, ks 0,1) + B(rb=w, ks 0,1).
//
// mfma_i32_32x32x32_i8 (HW-verified r8/r9/r10): per wave 4mf x 2nf, output
// 128x64, acc 128 AGPR. launch_bounds (512,2) -- (512,4) spills the acc
// (round-8 catastrophe); reg total ~210 of 256.
// ---------------------------------------------------------------------------
__global__ __launch_bounds__(512, 2) void gemm_i8_256(
    const signed char* __restrict__ Aq,
    const signed char* __restrict__ Bq,
    const float* __restrict__ bias,
    const float* __restrict__ act_scale,
    const float* __restrict__ wscale,
    float* __restrict__ out)
{
    __shared__ signed char lds[131072];   // 4 ring buffers x 32KB

    const int nbn = N_DIM / 256;                 // 16
    const int nwg = (M_DIM / 256) * nbn;         // 1024, %8==0
    int bid = blockIdx.x;
    int wg  = (bid & 7) * (nwg >> 3) + (bid >> 3);   // T1 XCD swizzle, bijective
    int bm  = wg / nbn;
    int bn  = wg % nbn;

    int tid  = threadIdx.x;
    int wave = tid >> 6;
    int lane = tid & 63;
    int wm_i = wave >> 2;      // 0..1  (128-row half)
    int wn_i = wave & 3;       // 0..3  (64-col quarter)

    const signed char* Ag = Aq + (size_t)bm * 256 * K_DIM;
    const signed char* Bg = Bq + (size_t)bn * 256 * K_DIM;

    // ---- staging source (per-lane inverse of the LDS unit layout) ----------
    int srow = ((lane ^ (lane >> 3)) & 3) * 8 + ((lane >> 3) & 7);
    int sg   = ((lane >> 2) ^ (lane >> 5)) & 1;
    size_t rowK = (size_t)srow * K_DIM + sg * 16;
    const signed char* Asrc = Ag + (size_t)(wave * 32) * K_DIM + rowK;
    const signed char* Bsrc = Bg + (size_t)(wave * 32) * K_DIM + rowK;

    // ---- reader per-lane offset within a unit ------------------------------
    int laneoff = (lane & 7) * 128
                + (((lane & 7) ^ ((lane >> 5) << 2) ^ ((lane >> 3) & 3)) * 16);
    int abase = wm_i * 8192;             // + mf*2048 + ks*1024 + laneoff
    int bbase = 16384 + wn_i * 4096;     // + nf*2048 + ks*1024 + laneoff

    // stage the 2 A-units + 2 B-units this wave owns for K-tile `tile`
#define STAGE_TILE(tile) do {                                                        \
    int _db = ((tile) & 3) * 32768;                                                  \
    _Pragma("unroll")                                                                \
    for (int ks = 0; ks < 2; ++ks) {                                                 \
        __builtin_amdgcn_global_load_lds(                                            \
            (const __attribute__((address_space(1))) void*)                          \
                (Asrc + (size_t)(tile) * 64 + ks * 32),                              \
            (__attribute__((address_space(3))) void*)                                \
                (lds + _db + (wave * 2 + ks) * 1024), 16, 0, 0);                     \
        __builtin_amdgcn_global_load_lds(                                            \
            (const __attribute__((address_space(1))) void*)                          \
                (Bsrc + (size_t)(tile) * 64 + ks * 32),                              \
            (__attribute__((address_space(3))) void*)                                \
                (lds + _db + 16384 + (wave * 2 + ks) * 1024), 16, 0, 0);             \
    }                                                                                \
} while (0)

    i32x16 acc[4][2] = {};
    i32x4 af[2][4], bf[2][2];   // [ks][mf]/[ks][nf], all statically indexed

    // ---- prologue: stage tiles 0,1,2; retire tile 0 (counted) --------------
    STAGE_TILE(0); STAGE_TILE(1); STAGE_TILE(2);
    asm volatile("s_waitcnt vmcnt(8)" ::: "memory");   // S(0) landed
    BARRIER();

    for (int t = 0; t < NT2; ++t) {
        const int cb = (t & 3) * 32768;

        if (t + 3 < NT2) STAGE_TILE(t + 3);

#pragma unroll
        for (int ks = 0; ks < 2; ++ks) {
#pragma unroll
            for (int mf = 0; mf < 4; ++mf)
                af[ks][mf] = *(const i32x4*)(lds + cb + abase + mf * 2048
                                             + ks * 1024 + laneoff);
#pragma unroll
            for (int nf = 0; nf < 2; ++nf)
                bf[ks][nf] = *(const i32x4*)(lds + cb + bbase + nf * 2048
                                             + ks * 1024 + laneoff);
        }

        __builtin_amdgcn_s_setprio(1);
#pragma unroll
        for (int ks = 0; ks < 2; ++ks)
#pragma unroll
            for (int mf = 0; mf < 4; ++mf)
#pragma unroll
                for (int nf = 0; nf < 2; ++nf)
                    acc[mf][nf] = __builtin_amdgcn_mfma_i32_32x32x32_i8(
                        af[ks][mf], bf[ks][nf], acc[mf][nf], 0, 0, 0);
        __builtin_amdgcn_s_setprio(0);

        if (t < NT2 - 1) {
            asm volatile("s_waitcnt lgkmcnt(0)" ::: "memory");  // WAR: my reads done
            if (t < NT2 - 3)        asm volatile("s_waitcnt vmcnt(8)" ::: "memory");
            else if (t == NT2 - 3)  asm volatile("s_waitcnt vmcnt(4)" ::: "memory");
            else                    asm volatile("s_waitcnt vmcnt(0)" ::: "memory");
            BARRIER();
        }
    }
#undef STAGE_TILE

    // ---- epilogue: out = acc * (sa * sw[o]) + bias[o] ----------------------
    float sa = act_scale[0];
#pragma unroll
    for (int nf = 0; nf < 2; ++nf) {
        int o = bn * 256 + wn_i * 64 + nf * 32 + (lane & 31);
        float sw = sa * wscale[o];
        float bv = bias[o];
#pragma unroll
        for (int mf = 0; mf < 4; ++mf) {
            int rowb = bm * 256 + wm_i * 128 + mf * 32 + 4 * (lane >> 5);
#pragma unroll
            for (int r = 0; r < 16; ++r) {
                int grow = rowb + (r & 3) + 8 * (r >> 2);
                out[(size_t)grow * N_DIM + o] = (float)acc[mf][nf][r] * sw + bv;
            }
        }
    }
}

// ---------------------------------------------------------------------------
// insurance fallback if ws_size < 80MB (should never trigger)
// ---------------------------------------------------------------------------
__global__ void fallback_kernel(
    const float* __restrict__ x, const float* __restrict__ w,
    const float* __restrict__ bias,
    const float* __restrict__ act_scale, const float* __restrict__ wscale,
    const int* __restrict__ act_zp, const int* __restrict__ wzp,
    float* __restrict__ out)
{
    size_t idx = (size_t)blockIdx.x * blockDim.x + threadIdx.x;
    if (idx >= (size_t)M_DIM * N_DIM) return;
    int m = (int)(idx >> 12);
    int o = (int)(idx & 4095);
    float sx = act_scale[0], zx = (float)act_zp[0];
    float sw = wscale[o],    zw = (float)wzp[o];
    float acc = 0.f;
    for (int k = 0; k < K_DIM; ++k) {
        float qx = fminf(fmaxf(rintf(x[(size_t)m * K_DIM + k] / sx) + zx, -128.f), 127.f) - zx;
        float qw = fminf(fmaxf(rintf(w[(size_t)o * K_DIM + k] / sw) + zw, -128.f), 127.f) - zw;
        acc += (qx * sx) * (qw * sw);
    }
    out[idx] = acc + bias[o];
}

// ---------------------------------------------------------------------------
extern "C" void kernel_launch(void* const* d_in, const int* in_sizes, int n_in,
                              void* d_out, int out_size, void* d_ws, size_t ws_size,
                              hipStream_t stream)
{
    const float* x    = (const float*)d_in[0];
    const float* w    = (const float*)d_in[1];
    const float* bias = (const float*)d_in[2];
    const float* asc  = (const float*)d_in[3];
    const float* wsc  = (const float*)d_in[4];
    const int*   azp  = (const int*)d_in[5];
    const int*   wzp  = (const int*)d_in[6];
    float* out = (float*)d_out;

    size_t xq_bytes = (size_t)M_DIM * K_DIM;   // 64 MiB
    size_t wq_bytes = (size_t)N_DIM * K_DIM;   // 16 MiB

    if (ws_size < xq_bytes + wq_bytes) {
        int total = M_DIM * N_DIM;
        fallback_kernel<<<(total + 255) / 256, 256, 0, stream>>>(
            x, w, bias, asc, wsc, azp, wzp, out);
        return;
    }

    signed char* xq = (signed char*)d_ws;
    signed char* wq = (signed char*)d_ws + xq_bytes;

    quant_x_kernel<<<(M_DIM * (K_DIM / 16)) / 256, 256, 0, stream>>>(x, asc, azp, xq);
    quant_w_kernel<<<(N_DIM * (K_DIM / 16)) / 256, 256, 0, stream>>>(w, wsc, wzp, wq);
    gemm_i8_256<<<(M_DIM / 256) * (N_DIM / 256), 512, 0, stream>>>(
        xq, wq, bias, asc, wsc, out);
}